// Round 1
// baseline (1082.837 us; speedup 1.0000x reference)
//
#include <hip/hip_runtime.h>

// RK4 neural-ODE integrator for f(y) = tanh(y W1 + b1) W2 + b2
// S=3, B=1024, D=32, H=128, T=256  ->  3072 independent rows, 255 RK4 steps.
//
// Design: one wave (64 lanes) per row, wave-synchronous (no __syncthreads).
//   - Weights live in VGPRs: lane p holds W1 columns j=2p,2p+1 (64 regs) and
//     W2 rows j in [64*jh, 64*jh+64) for its output dim d=p&31 (64 regs).
//   - Phase 1 (y->h): y_d broadcast via v_readlane -> SGPR, FMA with reg W1.
//   - h round-trips per-wave LDS (ds_write_b64 / 16x broadcast ds_read_b128).
//   - Phase 2 (h->o): 64 FMAs vs reg W2, halves summed via ds_bpermute.
//   - DS ops within a wave are ordered; wave_barrier() pins compiler order.

__device__ __forceinline__ float fast_tanh(float x) {
  // tanh(x) = (e^{2x}-1)/(e^{2x}+1); e^{2x} = 2^{x * 2*log2(e)}
  // clamp positive side so (inf-1)/(inf+1) can't produce NaN; tanh(15)==1.0f in fp32
  float a = fminf(x, 15.0f) * 2.885390081777927f;
  float t = __builtin_amdgcn_exp2f(a);
  return (t - 1.0f) * __builtin_amdgcn_rcpf(t + 1.0f);
}

__device__ __forceinline__ float rl(float v, int lane) {
  return __int_as_float(__builtin_amdgcn_readlane(__float_as_int(v), lane));
}

__launch_bounds__(256, 3)
__global__ void rk4_ode_kernel(const float* __restrict__ fp,   // [3072,32]
                               const float* __restrict__ ts,   // [256]
                               const float* __restrict__ W1,   // [32,128]
                               const float* __restrict__ b1,   // [128]
                               const float* __restrict__ W2,   // [128,32]
                               const float* __restrict__ b2,   // [32]
                               float* __restrict__ out) {      // [3072,256,32]
  __shared__ float hbuf[4 * 128];

  const int tid = threadIdx.x;
  const int wv  = tid >> 6;        // wave within block (0..3)
  const int p   = tid & 63;        // lane
  const int d   = p & 31;          // output/state dim owned by this lane
  const int jh  = p >> 5;          // which half of the hidden dim (phase 2)
  const int row = blockIdx.x * 4 + wv;   // grid = 768 blocks * 4 waves = 3072 rows

  // ---- weight slices into registers (reused 1020x) ----
  float w1a[32], w1b[32];          // W1[d][2p], W1[d][2p+1]
  const float2* W1v = reinterpret_cast<const float2*>(W1);
#pragma unroll
  for (int dd = 0; dd < 32; ++dd) {
    float2 w = W1v[dd * 64 + p];
    w1a[dd] = w.x; w1b[dd] = w.y;
  }
  const float2 b1v = reinterpret_cast<const float2*>(b1)[p];

  float w2r[64];                   // W2[64*jh + i][d]
#pragma unroll
  for (int i = 0; i < 64; ++i)
    w2r[i] = W2[(jh * 64 + i) * 32 + d];
  const float b2i = (jh == 0) ? b2[d] : 0.0f;

  // ---- RK4 state (distributed: lane p holds dim d; duplicated in both halves) ----
  float y0   = fp[row * 32 + d];
  float ycur = y0;
  float kacc = 0.0f;

  float* outrow = out + (size_t)row * (256 * 32);
  if (p < 32) outrow[d] = y0;      // t = 0 snapshot

  float* hw = &hbuf[wv * 128];
  const int pairaddr = (p ^ 32) << 2;   // bpermute byte address of partner lane

  for (int t = 0; t < 255; ++t) {
    const float dt = ts[t + 1] - ts[t];           // uniform -> SGPR
#pragma unroll
    for (int st = 0; st < 4; ++st) {
      // ---- phase 1: h_j = tanh(b1_j + sum_d y_d * W1[d][j]), lane owns j=2p,2p+1
      float a0 = b1v.x, a1 = b1v.y;
#pragma unroll
      for (int dd = 0; dd < 32; ++dd) {
        float s = rl(ycur, dd);                   // wave-uniform scalar
        a0 = fmaf(s, w1a[dd], a0);
        a1 = fmaf(s, w1b[dd], a1);
      }
      reinterpret_cast<float2*>(hw)[p] = make_float2(fast_tanh(a0), fast_tanh(a1));
      __builtin_amdgcn_wave_barrier();            // keep write before reads

      // ---- phase 2: o_d = b2_d + sum_j h_j * W2[j][d], lane sums its j-half
      float po = b2i;
      const float4* h4 = reinterpret_cast<const float4*>(hw) + jh * 16;
#pragma unroll
      for (int i = 0; i < 16; ++i) {
        float4 hv = h4[i];
        po = fmaf(hv.x, w2r[4 * i + 0], po);
        po = fmaf(hv.y, w2r[4 * i + 1], po);
        po = fmaf(hv.z, w2r[4 * i + 2], po);
        po = fmaf(hv.w, w2r[4 * i + 3], po);
      }
      __builtin_amdgcn_wave_barrier();            // keep reads before next write
      float k = po + __int_as_float(
                    __builtin_amdgcn_ds_bpermute(pairaddr, __float_as_int(po)));

      // ---- RK4 stage combination ----
      if (st == 0) {
        kacc = k;                  ycur = fmaf(0.5f * dt, k, y0);
      } else if (st == 1) {
        kacc = fmaf(2.0f, k, kacc); ycur = fmaf(0.5f * dt, k, y0);
      } else if (st == 2) {
        kacc = fmaf(2.0f, k, kacc); ycur = fmaf(dt, k, y0);
      } else {
        kacc = kacc + k;
        y0   = fmaf(dt * (1.0f / 6.0f), kacc, y0);
        ycur = y0;
      }
    }
    if (p < 32) outrow[(t + 1) * 32 + d] = y0;
  }
}

extern "C" void kernel_launch(void* const* d_in, const int* in_sizes, int n_in,
                              void* d_out, int out_size, void* d_ws, size_t ws_size,
                              hipStream_t stream) {
  const float* fp = (const float*)d_in[0];   // first_point [3,1024,32]
  const float* ts = (const float*)d_in[1];   // time_steps [256]
  const float* W1 = (const float*)d_in[2];   // [32,128]
  const float* b1 = (const float*)d_in[3];   // [128]
  const float* W2 = (const float*)d_in[4];   // [128,32]
  const float* b2 = (const float*)d_in[5];   // [32]
  float* out = (float*)d_out;                // [3,1024,256,32]

  // 3072 rows, 1 wave/row, 4 waves/block -> 768 blocks
  rk4_ode_kernel<<<768, 256, 0, stream>>>(fp, ts, W1, b1, W2, b2, out);
}

// Round 2
// 1066.455 us; speedup vs baseline: 1.0154x; 1.0154x over previous
//
#include <hip/hip_runtime.h>

// RK4 neural-ODE integrator for f(y) = tanh(y W1 + b1) W2 + b2
// S=3, B=1024, D=32, H=128, T=256  ->  3072 independent rows, 255 RK4 steps.
//
// One wave (64 lanes) per row, wave-synchronous (no __syncthreads).
// ROUND 2 change: weights held in 128 NAMED scalar floats (macro-expanded) so
// they can never be demoted to scratch (R1: VGPR=80, FETCH=388MB showed the
// w1a[32]/w1b[32]/w2r[64] arrays were scratch-lowered and re-loaded per eval).
//   - lane p: W1 cols j=2p,2p+1 (64 regs); W2 rows [64*jh,64*jh+64) for d=p&31.
//   - Phase 1 (y->h): y_d broadcast via v_readlane (SGPR src on v_fma).
//   - h round-trips per-wave LDS (1x ds_write_b64 / 16x broadcast ds_read_b128).
//   - Phase 2 halves summed via ds_bpermute with partner lane p^32.

__device__ __forceinline__ float fast_tanh(float x) {
  // tanh(x) = 1 - 2/(e^{2x}+1);  e^{2x} = 2^(x*2*log2 e).  5 VALU ops.
  // x->+inf: t=inf, rcp=0 -> 1.  x->-inf: t=0, rcp(1)=1 -> -1. No clamp needed.
  float t = __builtin_amdgcn_exp2f(x * 2.885390081777927f);
  return fmaf(-2.0f, __builtin_amdgcn_rcpf(t + 1.0f), 1.0f);
}

__device__ __forceinline__ float rl(float v, int lane) {
  return __int_as_float(__builtin_amdgcn_readlane(__float_as_int(v), lane));
}

#define REP32(X) \
  X(0) X(1) X(2) X(3) X(4) X(5) X(6) X(7) X(8) X(9) X(10) X(11) X(12) X(13) \
  X(14) X(15) X(16) X(17) X(18) X(19) X(20) X(21) X(22) X(23) X(24) X(25)   \
  X(26) X(27) X(28) X(29) X(30) X(31)

#define REP64(X) REP32(X) \
  X(32) X(33) X(34) X(35) X(36) X(37) X(38) X(39) X(40) X(41) X(42) X(43)   \
  X(44) X(45) X(46) X(47) X(48) X(49) X(50) X(51) X(52) X(53) X(54) X(55)   \
  X(56) X(57) X(58) X(59) X(60) X(61) X(62) X(63)

__launch_bounds__(256, 3)
__global__ void rk4_ode_kernel(const float* __restrict__ fp,   // [3072,32]
                               const float* __restrict__ ts,   // [256]
                               const float* __restrict__ W1,   // [32,128]
                               const float* __restrict__ b1,   // [128]
                               const float* __restrict__ W2,   // [128,32]
                               const float* __restrict__ b2,   // [32]
                               float* __restrict__ out) {      // [3072,256,32]
  __shared__ float hbuf[4 * 128];

  const int tid = threadIdx.x;
  const int wv  = tid >> 6;        // wave within block (0..3)
  const int p   = tid & 63;        // lane
  const int d   = p & 31;          // output/state dim owned by this lane
  const int jh  = p >> 5;          // which hidden-half this lane sums (phase 2)
  const int row = blockIdx.x * 4 + wv;   // 768 blocks * 4 waves = 3072 rows

  // ---- W1 slice: 64 named scalars (never scratch-lowered) ----
  const float2* W1v = reinterpret_cast<const float2*>(W1);
#define LOADW1(dd) \
  const float2 w1t_##dd = W1v[dd * 64 + p]; \
  const float w1a_##dd = w1t_##dd.x, w1b_##dd = w1t_##dd.y;
  REP32(LOADW1)
#undef LOADW1
  const float2 b1v = reinterpret_cast<const float2*>(b1)[p];

  // ---- W2 slice: 64 named scalars ----
  const float* W2base = W2 + (jh << 6) * 32 + d;
#define LOADW2(i) const float w2_##i = W2base[i * 32];
  REP64(LOADW2)
#undef LOADW2
  const float b2i = (jh == 0) ? b2[d] : 0.0f;

  // ---- RK4 state (lane p holds dim d, duplicated across halves) ----
  float y0   = fp[row * 32 + d];
  float ycur = y0;
  float kacc = 0.0f;

  float* outrow = out + (size_t)row * (256 * 32);
  if (p < 32) outrow[d] = y0;      // t = 0 snapshot

  float* hw = &hbuf[wv * 128];
  const int pairaddr = (p ^ 32) << 2;   // bpermute byte addr of partner lane

  for (int t = 0; t < 255; ++t) {
    const float dt = ts[t + 1] - ts[t];           // uniform -> SGPR
#pragma unroll
    for (int st = 0; st < 4; ++st) {
      // ---- phase 1: h_j = tanh(b1_j + sum_d y_d*W1[d][j]), lane owns 2 j's
      float a0 = b1v.x, a1 = b1v.y;
#define P1(dd) { float s = rl(ycur, dd); \
                 a0 = fmaf(s, w1a_##dd, a0); a1 = fmaf(s, w1b_##dd, a1); }
      REP32(P1)
#undef P1
      reinterpret_cast<float2*>(hw)[p] = make_float2(fast_tanh(a0), fast_tanh(a1));
      __builtin_amdgcn_wave_barrier();            // write before reads

      // ---- phase 2: o_d = b2_d + sum_j h_j*W2[j][d]; lane sums its j-half
      float po = b2i;
      const float4* h4 = reinterpret_cast<const float4*>(hw) + (jh << 4);
#define P2(i, iA, iB, iC, iD) { const float4 hv = h4[i]; \
        po = fmaf(hv.x, w2_##iA, po); po = fmaf(hv.y, w2_##iB, po);          \
        po = fmaf(hv.z, w2_##iC, po); po = fmaf(hv.w, w2_##iD, po); }
      P2(0, 0, 1, 2, 3)    P2(1, 4, 5, 6, 7)    P2(2, 8, 9, 10, 11)
      P2(3, 12, 13, 14, 15) P2(4, 16, 17, 18, 19) P2(5, 20, 21, 22, 23)
      P2(6, 24, 25, 26, 27) P2(7, 28, 29, 30, 31) P2(8, 32, 33, 34, 35)
      P2(9, 36, 37, 38, 39) P2(10, 40, 41, 42, 43) P2(11, 44, 45, 46, 47)
      P2(12, 48, 49, 50, 51) P2(13, 52, 53, 54, 55) P2(14, 56, 57, 58, 59)
      P2(15, 60, 61, 62, 63)
#undef P2
      __builtin_amdgcn_wave_barrier();            // reads before next write
      float k = po + __int_as_float(
                    __builtin_amdgcn_ds_bpermute(pairaddr, __float_as_int(po)));

      // ---- RK4 stage combination ----
      if (st == 0) {
        kacc = k;                   ycur = fmaf(0.5f * dt, k, y0);
      } else if (st == 1) {
        kacc = fmaf(2.0f, k, kacc); ycur = fmaf(0.5f * dt, k, y0);
      } else if (st == 2) {
        kacc = fmaf(2.0f, k, kacc); ycur = fmaf(dt, k, y0);
      } else {
        kacc = kacc + k;
        y0   = fmaf(dt * (1.0f / 6.0f), kacc, y0);
        ycur = y0;
      }
    }
    if (p < 32) outrow[(t + 1) * 32 + d] = y0;
  }
}

extern "C" void kernel_launch(void* const* d_in, const int* in_sizes, int n_in,
                              void* d_out, int out_size, void* d_ws, size_t ws_size,
                              hipStream_t stream) {
  const float* fp = (const float*)d_in[0];   // first_point [3,1024,32]
  const float* ts = (const float*)d_in[1];   // time_steps [256]
  const float* W1 = (const float*)d_in[2];   // [32,128]
  const float* b1 = (const float*)d_in[3];   // [128]
  const float* W2 = (const float*)d_in[4];   // [128,32]
  const float* b2 = (const float*)d_in[5];   // [32]
  float* out = (float*)d_out;                // [3,1024,256,32]

  rk4_ode_kernel<<<768, 256, 0, stream>>>(fp, ts, W1, b1, W2, b2, out);
}

// Round 3
// 1052.472 us; speedup vs baseline: 1.0289x; 1.0133x over previous
//
#include <hip/hip_runtime.h>

// RK4 neural-ODE integrator for f(y) = tanh(y W1 + b1) W2 + b2
// S=3, B=1024, D=32, H=128, T=256  ->  3072 rows, 255 RK4 steps, 1 wave/row.
//
// ROUND 3: R1/R2 both showed VGPR=80 (= the 6-waves/EU budget) + FETCH 388MB:
// the backend scheduler targets 6 waves/EU and SPILLS ~70 weight regs to
// scratch, reloading them every eval (launch_bounds arg2 is a MIN, not a max).
// Fix: 48 KB static LDS pins max occupancy to 3 blocks/CU (160/48) -> VGPR
// budget 512/3=168 -> the 128 weight floats stay in registers. Grid = 768
// blocks = exactly 3/CU resident, so no real occupancy is lost.
// Also: W1/b1 pre-scaled by 2*log2(e) (tanh -> 4 instr), phase 2 packed into
// v_pk_fma_f32 (h float4 halves + W2 pairs are register-adjacent).

typedef float f2 __attribute__((ext_vector_type(2)));
typedef float f4 __attribute__((ext_vector_type(4)));

__device__ __forceinline__ float rl(float v, int lane) {
  return __int_as_float(__builtin_amdgcn_readlane(__float_as_int(v), lane));
}

__device__ __forceinline__ f2 fma2(f2 a, f2 b, f2 c) {
#if __has_builtin(__builtin_elementwise_fma)
  return __builtin_elementwise_fma(a, b, c);   // -> v_pk_fma_f32
#else
  f2 r; r.x = fmaf(a.x, b.x, c.x); r.y = fmaf(a.y, b.y, c.y); return r;
#endif
}

// tanh(z) with z pre-scaled by 2*log2(e): tanh = 1 - 2/(2^z + 1)
__device__ __forceinline__ float tanh_scaled(float z) {
  float t = __builtin_amdgcn_exp2f(z);
  return fmaf(-2.0f, __builtin_amdgcn_rcpf(t + 1.0f), 1.0f);
}

#define REP32(X) \
  X(0) X(1) X(2) X(3) X(4) X(5) X(6) X(7) X(8) X(9) X(10) X(11) X(12) X(13) \
  X(14) X(15) X(16) X(17) X(18) X(19) X(20) X(21) X(22) X(23) X(24) X(25)   \
  X(26) X(27) X(28) X(29) X(30) X(31)

__launch_bounds__(256, 3)
__global__ void rk4_ode_kernel(const float* __restrict__ fp,   // [3072,32]
                               const float* __restrict__ ts,   // [256]
                               const float* __restrict__ W1,   // [32,128]
                               const float* __restrict__ b1,   // [128]
                               const float* __restrict__ W2,   // [128,32]
                               const float* __restrict__ b2,   // [32]
                               float* __restrict__ out) {      // [3072,256,32]
  // 48 KB: caps occupancy at 3 blocks/CU so the scheduler's VGPR budget is
  // 168 and the 128 weight values below are never spilled. Only the first
  // 512 floats are used (per-wave h buffers); the rest is deliberate padding.
  __shared__ float smem[12288];

  const int tid = threadIdx.x;
  const int wv  = tid >> 6;        // wave in block
  const int p   = tid & 63;        // lane
  const int d   = p & 31;          // state dim owned by this lane
  const int jh  = p >> 5;          // hidden-half this lane sums in phase 2
  const int row = blockIdx.x * 4 + wv;   // 768 blocks * 4 waves = 3072 rows

  const float C = 2.885390081777926814f;   // 2*log2(e), folded into W1/b1

  // ---- W1 slice (pre-scaled): lane p holds cols j=2p,2p+1 for all 32 d ----
  const float2* W1v = reinterpret_cast<const float2*>(W1);
#define LOADW1(dd) f2 w1_##dd; { const float2 t_ = W1v[dd * 64 + p]; \
                                 w1_##dd.x = t_.x * C; w1_##dd.y = t_.y * C; }
  REP32(LOADW1)
#undef LOADW1
  const float2 b1t = reinterpret_cast<const float2*>(b1)[p];
  const float b1a = b1t.x * C, b1b = b1t.y * C;

  // ---- W2 slice as 32 register pairs: rows [64*jh, 64*jh+64) for dim d ----
  const float* W2base = W2 + (jh << 6) * 32 + d;
#define LOADW2(i) f2 w2_##i; w2_##i.x = W2base[(2 * i) * 32]; \
                             w2_##i.y = W2base[(2 * i + 1) * 32];
  REP32(LOADW2)
#undef LOADW2
  const float b2i = (jh == 0) ? b2[d] : 0.0f;

  // ---- RK4 state (lane p holds dim d, duplicated across halves) ----
  float y0   = fp[row * 32 + d];
  float ycur = y0;
  float kacc = 0.0f;

  float* outrow = out + (size_t)row * (256 * 32);
  if (p < 32) outrow[d] = y0;      // t = 0 snapshot

  float* hw = &smem[wv * 128];
  const int pairaddr = (p ^ 32) << 2;   // bpermute byte addr of partner lane

  for (int t = 0; t < 255; ++t) {
    const float dt = ts[t + 1] - ts[t];           // uniform -> SGPR
#pragma unroll
    for (int st = 0; st < 4; ++st) {
      // phase 1: zs_j = C*(b1_j + sum_d y_d W1[d][j]); lane owns j=2p,2p+1
      float a0 = b1a, a1 = b1b;
#define P1(dd) { const float s_ = rl(ycur, dd); \
                 a0 = fmaf(s_, w1_##dd.x, a0); a1 = fmaf(s_, w1_##dd.y, a1); }
      REP32(P1)
#undef P1
      reinterpret_cast<f2*>(hw)[p] = (f2){tanh_scaled(a0), tanh_scaled(a1)};
      __builtin_amdgcn_wave_barrier();            // write before reads

      // phase 2: o_d = b2_d + sum_j h_j W2[j][d]; lane sums its 64-j half
      f2 po2 = {b2i, 0.0f};
      const f4* h4 = reinterpret_cast<const f4*>(hw) + (jh << 4);
#define P2(i, ia, ib) { const f4 hv = h4[i]; \
                        po2 = fma2(hv.xy, w2_##ia, po2); \
                        po2 = fma2(hv.zw, w2_##ib, po2); }
      P2(0, 0, 1)    P2(1, 2, 3)    P2(2, 4, 5)    P2(3, 6, 7)
      P2(4, 8, 9)    P2(5, 10, 11)  P2(6, 12, 13)  P2(7, 14, 15)
      P2(8, 16, 17)  P2(9, 18, 19)  P2(10, 20, 21) P2(11, 22, 23)
      P2(12, 24, 25) P2(13, 26, 27) P2(14, 28, 29) P2(15, 30, 31)
#undef P2
      __builtin_amdgcn_wave_barrier();            // reads before next write
      const float po = po2.x + po2.y;
      const float k = po + __int_as_float(
                    __builtin_amdgcn_ds_bpermute(pairaddr, __float_as_int(po)));

      // RK4 stage combination
      if (st == 0) {
        kacc = k;                   ycur = fmaf(0.5f * dt, k, y0);
      } else if (st == 1) {
        kacc = fmaf(2.0f, k, kacc); ycur = fmaf(0.5f * dt, k, y0);
      } else if (st == 2) {
        kacc = fmaf(2.0f, k, kacc); ycur = fmaf(dt, k, y0);
      } else {
        kacc = kacc + k;
        y0   = fmaf(dt * (1.0f / 6.0f), kacc, y0);
        ycur = y0;
      }
    }
    if (p < 32) outrow[(t + 1) * 32 + d] = y0;
  }
}

extern "C" void kernel_launch(void* const* d_in, const int* in_sizes, int n_in,
                              void* d_out, int out_size, void* d_ws, size_t ws_size,
                              hipStream_t stream) {
  const float* fp = (const float*)d_in[0];   // first_point [3,1024,32]
  const float* ts = (const float*)d_in[1];   // time_steps [256]
  const float* W1 = (const float*)d_in[2];   // [32,128]
  const float* b1 = (const float*)d_in[3];   // [128]
  const float* W2 = (const float*)d_in[4];   // [128,32]
  const float* b2 = (const float*)d_in[5];   // [32]
  float* out = (float*)d_out;                // [3,1024,256,32]

  rk4_ode_kernel<<<768, 256, 0, stream>>>(fp, ts, W1, b1, W2, b2, out);
}

// Round 4
// 913.123 us; speedup vs baseline: 1.1859x; 1.1526x over previous
//
#include <hip/hip_runtime.h>

// RK4 neural-ODE: f(y) = tanh(y W1 + b1) W2 + b2;  3072 rows x 255 steps.
// One wave per row, wave-synchronous.
//
// ROUND 4: two fixes driven by R1-R3 counters (VGPR pinned at 80, dur pinned
// at ~1100us regardless of VALU work):
//  (a) amdgpu_waves_per_eu(3,3): forces the allocator's budget to 512/3=168
//      VGPRs so the 128 weight floats actually stay in registers (R3 proved
//      the LDS-occupancy trick does NOT raise the VGPR budget).
//  (b) DS-pipe diet: phase 2 split 8-ways over hidden dim. Lane p, group
//      g=bits{0,1,5}(p), owns j in [16g,16g+16) and 4 outputs d=(p&0x1C)|m.
//      Only 4 ds_read_b128 per eval (was 16); group partials combined at
//      lane-distance ^1,^2 via DPP quad_perm (VALU pipe!) + one ^32 bpermute
//      after a cndmask select. h chunks stored at stride 20 floats so the 8
//      group-broadcast reads hit disjoint banks.

typedef float f2 __attribute__((ext_vector_type(2)));
typedef float f4 __attribute__((ext_vector_type(4)));

__device__ __forceinline__ float rl(float v, int lane) {
  return __int_as_float(__builtin_amdgcn_readlane(__float_as_int(v), lane));
}
__device__ __forceinline__ f2 fma2(f2 a, f2 b, f2 c) {
  return __builtin_elementwise_fma(a, b, c);
}
// tanh(z) with z pre-scaled by 2*log2(e): tanh = 1 - 2/(2^z + 1)
__device__ __forceinline__ float tanh_scaled(float z) {
  float t = __builtin_amdgcn_exp2f(z);
  return fmaf(-2.0f, __builtin_amdgcn_rcpf(t + 1.0f), 1.0f);
}
// quad_perm xor-1 / xor-2 (VALU-pipe cross-lane)
__device__ __forceinline__ float dpp_xor1(float x) {
  return __int_as_float(__builtin_amdgcn_update_dpp(
      0, __float_as_int(x), 0xB1, 0xF, 0xF, true));  // [1,0,3,2]
}
__device__ __forceinline__ float dpp_xor2(float x) {
  return __int_as_float(__builtin_amdgcn_update_dpp(
      0, __float_as_int(x), 0x4E, 0xF, 0xF, true));  // [2,3,0,1]
}
__device__ __forceinline__ f2 ldW2(const float* W2, int j, int d) {
  f2 r; r.x = W2[j * 32 + d]; r.y = W2[(j + 1) * 32 + d]; return r;
}

#define REP32(X) \
  X(0) X(1) X(2) X(3) X(4) X(5) X(6) X(7) X(8) X(9) X(10) X(11) X(12) X(13) \
  X(14) X(15) X(16) X(17) X(18) X(19) X(20) X(21) X(22) X(23) X(24) X(25)   \
  X(26) X(27) X(28) X(29) X(30) X(31)

__global__ void __launch_bounds__(256)
__attribute__((amdgpu_waves_per_eu(3, 3)))
rk4_ode_kernel(const float* __restrict__ fp,   // [3072,32]
               const float* __restrict__ ts,   // [256]
               const float* __restrict__ W1,   // [32,128]
               const float* __restrict__ b1,   // [128]
               const float* __restrict__ W2,   // [128,32]
               const float* __restrict__ b2,   // [32]
               float* __restrict__ out) {      // [3072,256,32]
  // per-wave h buffer: 8 chunks of 16 floats at stride 20 (bank stagger)
  __shared__ float smem[4 * 160];

  const int tid = threadIdx.x;
  const int wv  = tid >> 6;
  const int p   = tid & 63;
  const int row = blockIdx.x * 4 + wv;

  const int g  = (p & 3) | ((p >> 5) << 2);   // j-group: lane bits {0,1,5}
  const int j0 = g << 4;                      // 16 j's per group
  const int d0 = p & 0x1C;                    // outputs d0|m, m=0..3 (q=bits{2,3,4})

  const float C = 2.885390081777926814f;      // 2*log2(e) folded into W1/b1

  // ---- W1: lane p produces h_{2p}, h_{2p+1}; packed col-pairs, pre-scaled ----
  const float2* W1v = reinterpret_cast<const float2*>(W1);
#define LOADW1(dd) f2 w1_##dd; { const float2 t_ = W1v[dd * 64 + p]; \
                                 w1_##dd.x = t_.x * C; w1_##dd.y = t_.y * C; }
  REP32(LOADW1)
#undef LOADW1
  const float2 b1t = reinterpret_cast<const float2*>(b1)[p];
  const f2 b1v = {b1t.x * C, b1t.y * C};

  // ---- W2: rows [j0, j0+16) for 4 outputs d0|m, as j-pair f2 regs ----
#define LW2(m) \
  const f2 w2_##m##_0 = ldW2(W2, j0 + 0,  d0 | m); \
  const f2 w2_##m##_1 = ldW2(W2, j0 + 2,  d0 | m); \
  const f2 w2_##m##_2 = ldW2(W2, j0 + 4,  d0 | m); \
  const f2 w2_##m##_3 = ldW2(W2, j0 + 6,  d0 | m); \
  const f2 w2_##m##_4 = ldW2(W2, j0 + 8,  d0 | m); \
  const f2 w2_##m##_5 = ldW2(W2, j0 + 10, d0 | m); \
  const f2 w2_##m##_6 = ldW2(W2, j0 + 12, d0 | m); \
  const f2 w2_##m##_7 = ldW2(W2, j0 + 14, d0 | m);
  LW2(0) LW2(1) LW2(2) LW2(3)
#undef LW2
  const float b2l = b2[p & 31];

  // ---- RK4 state: lane p holds dim d = p&31 (valid on all 64 lanes) ----
  float y0   = fp[row * 32 + (p & 31)];
  float ycur = y0;
  float kacc = 0.0f;

  float* outrow = out + (size_t)row * (256 * 32);
  if (p < 32) outrow[p] = y0;

  // h LDS addressing: h_j stored at float index 20*(j>>4) + (j&15)
  float* hwbase = &smem[wv * 160];
  float* hwr    = hwbase + 20 * (p >> 3) + 2 * (p & 7);   // write f2 (j=2p,2p+1)
  const f4* hrd = reinterpret_cast<const f4*>(hwbase + 20 * g); // 4x b128 reads
  const int pairaddr = (p ^ 32) << 2;

  for (int t = 0; t < 255; ++t) {
    const float dt = ts[t + 1] - ts[t];
#pragma unroll
    for (int st = 0; st < 4; ++st) {
      // ---- phase 1: z = C*(b1 + y.W1) for cols 2p,2p+1 (two acc chains) ----
      f2 ae = b1v, ao = {0.0f, 0.0f};
#define P1(dd) { const float s_ = rl(ycur, dd); const f2 ss = {s_, s_};      \
                 if ((dd) & 1) ao = fma2(ss, w1_##dd, ao);                   \
                 else          ae = fma2(ss, w1_##dd, ae); }
      REP32(P1)
#undef P1
      const f2 a = ae + ao;
      *reinterpret_cast<f2*>(hwr) = (f2){tanh_scaled(a.x), tanh_scaled(a.y)};
      __builtin_amdgcn_wave_barrier();          // write before reads

      // ---- phase 2: 16 h-floats for my j-group vs 4 output columns ----
      f2 acc0 = {0,0}, acc1 = {0,0}, acc2 = {0,0}, acc3 = {0,0};
      {
        const f4 r0 = hrd[0], r1 = hrd[1];
#define ACCA(m) acc##m = fma2(r0.xy, w2_##m##_0, acc##m); \
                acc##m = fma2(r0.zw, w2_##m##_1, acc##m); \
                acc##m = fma2(r1.xy, w2_##m##_2, acc##m); \
                acc##m = fma2(r1.zw, w2_##m##_3, acc##m);
        ACCA(0) ACCA(1) ACCA(2) ACCA(3)
#undef ACCA
        const f4 r2 = hrd[2], r3 = hrd[3];
#define ACCB(m) acc##m = fma2(r2.xy, w2_##m##_4, acc##m); \
                acc##m = fma2(r2.zw, w2_##m##_5, acc##m); \
                acc##m = fma2(r3.xy, w2_##m##_6, acc##m); \
                acc##m = fma2(r3.zw, w2_##m##_7, acc##m);
        ACCB(0) ACCB(1) ACCB(2) ACCB(3)
#undef ACCB
      }
      __builtin_amdgcn_wave_barrier();          // reads before next write

      // ---- combine group partials: ^1,^2 via DPP (VALU), then select, ^32 ----
      float k0 = acc0.x + acc0.y, k1 = acc1.x + acc1.y;
      float k2 = acc2.x + acc2.y, k3 = acc3.x + acc3.y;
      k0 += dpp_xor1(k0); k1 += dpp_xor1(k1); k2 += dpp_xor1(k2); k3 += dpp_xor1(k3);
      k0 += dpp_xor2(k0); k1 += dpp_xor2(k1); k2 += dpp_xor2(k2); k3 += dpp_xor2(k3);
      const float s01 = (p & 1) ? k1 : k0;
      const float s23 = (p & 1) ? k3 : k2;
      const float ks  = (p & 2) ? s23 : s01;    // my output's quad partial
      const float k = ks + b2l + __int_as_float(
          __builtin_amdgcn_ds_bpermute(pairaddr, __float_as_int(ks)));

      // ---- RK4 stage combination ----
      if (st == 0) {
        kacc = k;                   ycur = fmaf(0.5f * dt, k, y0);
      } else if (st == 1) {
        kacc = fmaf(2.0f, k, kacc); ycur = fmaf(0.5f * dt, k, y0);
      } else if (st == 2) {
        kacc = fmaf(2.0f, k, kacc); ycur = fmaf(dt, k, y0);
      } else {
        kacc = kacc + k;
        y0   = fmaf(dt * (1.0f / 6.0f), kacc, y0);
        ycur = y0;
      }
    }
    if (p < 32) outrow[(t + 1) * 32 + p] = y0;
  }
}

extern "C" void kernel_launch(void* const* d_in, const int* in_sizes, int n_in,
                              void* d_out, int out_size, void* d_ws, size_t ws_size,
                              hipStream_t stream) {
  const float* fp = (const float*)d_in[0];   // first_point [3,1024,32]
  const float* ts = (const float*)d_in[1];   // time_steps [256]
  const float* W1 = (const float*)d_in[2];   // [32,128]
  const float* b1 = (const float*)d_in[3];   // [128]
  const float* W2 = (const float*)d_in[4];   // [128,32]
  const float* b2 = (const float*)d_in[5];   // [32]
  float* out = (float*)d_out;                // [3,1024,256,32]

  rk4_ode_kernel<<<768, 256, 0, stream>>>(fp, ts, W1, b1, W2, b2, out);
}